// Round 11
// baseline (673.051 us; speedup 1.0000x reference)
//
#include <hip/hip_runtime.h>
#include <hip/hip_cooperative_groups.h>
#include <hip/hip_bf16.h>
#include <math.h>

namespace cg = cooperative_groups;

#define B_SZ   8192
#define S_SZ   16
#define D_SZ   128
#define HID_SZ 1024
#define NUMF_SZ 103
#define GCN_SZ 40
#define G_B    4                 // batch elements per encoder tile (64 rows)
#define NBLK   (B_SZ / G_B)      // 2048 encoder tiles
#define SBLK   512               // BN-stats tiles (16 rows each)
#define STRD   136               // LDS row stride (shorts), pad 8

typedef short bh8 __attribute__((ext_vector_type(8)));   // 8 bf16 (4 VGPRs)
typedef float fx4 __attribute__((ext_vector_type(4)));   // MFMA accumulator
typedef unsigned short us4 __attribute__((ext_vector_type(4))); // 4 bf16 (8B)

__device__ __forceinline__ fx4 mfma16(bh8 a, bh8 b, fx4 c) {
    return __builtin_amdgcn_mfma_f32_16x16x32_bf16(a, b, c, 0, 0, 0);
}
__device__ __forceinline__ unsigned short f2b(float f) {
    union { __hip_bfloat16 b; unsigned short u; } cv;
    cv.b = __float2bfloat16(f);
    return cv.u;
}
__device__ __forceinline__ float bu2f(unsigned short u) {
    return __uint_as_float(((unsigned)u) << 16);
}

struct KArgs {
    const float *x, *gcn;
    const float *bq, *bk, *bv, *bo, *ln1g, *ln1b, *b1, *b2p, *ln2g, *ln2b, *Wf;
    const float *Wq, *Wk, *Wv, *Wo, *W1, *W2;          // raw weights (prep)
    unsigned short *WswQ, *WswK, *WswV, *WswO, *Wsw1, *Wsw2;
    float *PEt;
    const float *num, *Wn, *bnum;
    float *ssum, *ssq;
    const float *bng, *bnb, *bfin;
    float *acc1;
    float *out;
};

// ONE cooperative kernel (512 persistent blocks = 2/CU):
//  P0: weight swizzle + PE table + zero stats   (was prep_weights + memset)
//  -- grid.sync --
//  P1: 4 encoder tiles/block + 1 BN-stats tile/block (atomics)
//  -- grid.sync --
//  P2: per-block BN-fold coefficients (redundant, cheap) + final sigmoid rows
// Removes all inter-dispatch chain overhead (~13-25us per dispatch, R7->R10).
__global__ __launch_bounds__(256, 2) void mega_coop(KArgs a)
{
    __shared__ unsigned short ACT[64][STRD];  // activations / LN2 output
    __shared__ unsigned short Qb[64][STRD];   // Q -> ctx -> FF1 chunk (even)
    __shared__ unsigned short Kb[64][STRD];   // K -> H (post-LN1)
    __shared__ unsigned short Vb[64][STRD];   // V^T (per-head) -> FF1 chunk (odd)
    __shared__ float2 LNp2[64][4];            // per-row per-wave (sum, sumsq)
    __shared__ unsigned short Pb[4][16][16];  // per-wave P tile (softmax probs)

    unsigned short* Vb4 = &Vb[0][0];          // V^T alias: [E(4)][g(8)][dh(16)][uk(16)]

    const int t = threadIdx.x;
    const int w = t >> 6, lane = t & 63;
    const int q = lane >> 4, ln = lane & 15;

    // ===================== P0: prep (grid-stride) =====================
    for (int j = blockIdx.x * 256 + t; j < 262144; j += gridDim.x * 256) {
        if (j < 2048) {  // PE table [16][128]
            int s = j >> 7, c = j & 127;
            float expo = (float)((c >> 1) * 2) * (1.0f / 128.0f);
            float denom = powf(10000.0f, expo);
            float ang = (float)s / denom;
            a.PEt[j] = (c & 1) ? cosf(ang) : sinf(ang);
        }
        if (j < 2 * 16384) {   // QKVO: src [l][k=128][n=128]
            int r = j & 16383, l = j >> 14;
            int k = r >> 7, n = r & 127;
            int dst = (((l * 8 + (n >> 4)) * 4 + (k >> 5)) * 64 +
                       (((k >> 3) & 3) * 16 + (n & 15))) * 8 + (k & 7);
            a.WswQ[dst] = f2b(a.Wq[j]); a.WswK[dst] = f2b(a.Wk[j]);
            a.WswV[dst] = f2b(a.Wv[j]); a.WswO[dst] = f2b(a.Wo[j]);
        }
        {   // W1: src [l][k=128][n=1024]
            int l = j >> 17, r = j & 131071;
            int k = r >> 10, n = r & 1023;
            int dst = (((l * 64 + (n >> 4)) * 4 + (k >> 5)) * 64 +
                       (((k >> 3) & 3) * 16 + (n & 15))) * 8 + (k & 7);
            a.Wsw1[dst] = f2b(a.W1[j]);
        }
        {   // W2: src [l][k=1024][n=128]
            int l = j >> 17, r = j & 131071;
            int k = r >> 7, n = r & 127;
            int dst = (((l * 8 + (n >> 4)) * 32 + (k >> 5)) * 64 +
                       (((k >> 3) & 3) * 16 + (n & 15))) * 8 + (k & 7);
            a.Wsw2[dst] = f2b(a.W2[j]);
        }
    }
    if (blockIdx.x == 0 && t < 256) a.ssum[t] = 0.f;   // ssum[128] | ssq[128]
    __threadfence();
    cg::this_grid().sync();

    // ===================== P1a: encoder tiles =====================
    for (int bt = blockIdx.x; bt < NBLK; bt += gridDim.x) {
        const int bbase = bt * G_B;

        // ---- load x + PE -> ACT (bf16) ----
        {
            const float4* xb = (const float4*)(a.x + (size_t)bbase * 2048);
            const float4* pe4 = (const float4*)a.PEt;
#pragma unroll
            for (int i = 0; i < 8; ++i) {
                int f4 = i * 256 + t;                  // 0..2047
                float4 xv = xb[f4];
                float4 pv = pe4[f4 & 511];
                int flat = f4 * 4;
                int row = flat >> 7, col = flat & 127;
                ushort4 pk = {f2b(xv.x + pv.x), f2b(xv.y + pv.y),
                              f2b(xv.z + pv.z), f2b(xv.w + pv.w)};
                *(ushort4*)&ACT[row][col] = pk;
            }
        }
        __syncthreads();

        for (int l = 0; l < 2; ++l) {
            // ================= QKV =================
            {
                bh8 afr[4][4];
#pragma unroll
                for (int mt = 0; mt < 4; ++mt)
#pragma unroll
                    for (int ks = 0; ks < 4; ++ks)
                        afr[mt][ks] = *(const bh8*)&ACT[mt * 16 + ln][ks * 32 + q * 8];
                // ---- Q and K: swapped-C, packed ushort4 stores ----
#pragma unroll
                for (int mtx = 0; mtx < 2; ++mtx) {
                    const unsigned short* Wm = (mtx == 0) ? a.WswQ + l * 16384 : a.WswK + l * 16384;
                    const float* bias = (mtx == 0) ? a.bq + l * 128 : a.bk + l * 128;
                    unsigned short (*dst)[STRD] = (mtx == 0) ? Qb : Kb;
#pragma unroll
                    for (int i2 = 0; i2 < 2; ++i2) {
                        int nt = w * 2 + i2;
                        bh8 wfr[4];
#pragma unroll
                        for (int ks = 0; ks < 4; ++ks)
                            wfr[ks] = *(const bh8*)(Wm + ((nt * 4 + ks) * 64 + lane) * 8);
                        int n0 = nt * 16 + q * 4;
                        fx4 bb4 = *(const fx4*)&bias[n0];
#pragma unroll
                        for (int mt = 0; mt < 4; ++mt) {
                            fx4 acc = {0.f, 0.f, 0.f, 0.f};
#pragma unroll
                            for (int ks = 0; ks < 4; ++ks) acc = mfma16(wfr[ks], afr[mt][ks], acc);
                            us4 o;
#pragma unroll
                            for (int r2 = 0; r2 < 4; ++r2) o[r2] = f2b(acc[r2] + bb4[r2]);
                            *(us4*)&dst[mt * 16 + ln][n0] = o;
                        }
                    }
                }
                // ---- V: normal-C orientation, scattered into V^T layout ----
#pragma unroll
                for (int i2 = 0; i2 < 2; ++i2) {
                    int nt = w * 2 + i2;
                    bh8 wfr[4];
#pragma unroll
                    for (int ks = 0; ks < 4; ++ks)
                        wfr[ks] = *(const bh8*)(a.WswV + l * 16384 + ((nt * 4 + ks) * 64 + lane) * 8);
                    int n = nt * 16 + ln;
                    float bb = a.bv[l * 128 + n];
#pragma unroll
                    for (int mt = 0; mt < 4; ++mt) {
                        fx4 acc = {0.f, 0.f, 0.f, 0.f};
#pragma unroll
                        for (int ks = 0; ks < 4; ++ks) acc = mfma16(afr[mt][ks], wfr[ks], acc);
#pragma unroll
                        for (int r2 = 0; r2 < 4; ++r2) {
                            int s = q * 4 + r2;
                            Vb4[(((mt * 8 + (s >> 1)) * 16) + ln) * 16 +
                                (((s & 1) << 3) | nt)] = f2b(acc[r2] + bb);
                        }
                    }
                }
            }
            __syncthreads();

            // ===== attention, MFMA-based, wave-local =====
            {
                const int E = w;
                const int rbase = E * 16 + (ln >> 3);
                const int ccol = (ln & 7) * 16;
#pragma unroll
                for (int g = 0; g < 8; ++g) {
                    bh8 kfr = 0, qfr = 0;
                    if (q < 2) {
                        kfr = *(const bh8*)&Kb[rbase + 2 * g][ccol + q * 8];
                        qfr = *(const bh8*)&Qb[rbase + 2 * g][ccol + q * 8];
                    }
                    fx4 st = mfma16(kfr, qfr, fx4{0.f, 0.f, 0.f, 0.f});
                    float p0 = st[0] * 0.25f, p1 = st[1] * 0.25f;
                    float p2 = st[2] * 0.25f, p3 = st[3] * 0.25f;
                    float mx = fmaxf(fmaxf(p0, p1), fmaxf(p2, p3));
                    mx = fmaxf(mx, __shfl_xor(mx, 16));
                    mx = fmaxf(mx, __shfl_xor(mx, 32));
                    p0 = __expf(p0 - mx); p1 = __expf(p1 - mx);
                    p2 = __expf(p2 - mx); p3 = __expf(p3 - mx);
                    float sm = (p0 + p1) + (p2 + p3);
                    sm += __shfl_xor(sm, 16);
                    sm += __shfl_xor(sm, 32);
                    float is = 1.0f / sm;
                    ushort4 pk = {f2b(p0 * is), f2b(p1 * is), f2b(p2 * is), f2b(p3 * is)};
                    *(ushort4*)&Pb[w][ln][q * 4] = pk;
                    bh8 vfr = 0, pfr = 0;
                    if (q < 2) {
                        vfr = *(const bh8*)&Vb4[(((E * 8 + g) * 16) + ln) * 16 + q * 8];
                        pfr = *(const bh8*)&Pb[w][ln][q * 8];
                    }
                    fx4 cx = mfma16(vfr, pfr, fx4{0.f, 0.f, 0.f, 0.f});
                    ushort4 ck = {f2b(cx[0]), f2b(cx[1]), f2b(cx[2]), f2b(cx[3])};
                    *(ushort4*)&Qb[rbase + 2 * g][ccol + q * 4] = ck;
                }
            }
            __syncthreads();

            // ========= O-proj (swapped-C) + residual + LN1 -> Kb (H) ========
            fx4 Cv[2][4];
            {
                bh8 cfr[4][4];
#pragma unroll
                for (int mt = 0; mt < 4; ++mt)
#pragma unroll
                    for (int ks = 0; ks < 4; ++ks)
                        cfr[mt][ks] = *(const bh8*)&Qb[mt * 16 + ln][ks * 32 + q * 8];
#pragma unroll
                for (int i2 = 0; i2 < 2; ++i2) {
                    int nt = w * 2 + i2, n0 = nt * 16 + q * 4;
                    bh8 wfr[4];
#pragma unroll
                    for (int ks = 0; ks < 4; ++ks)
                        wfr[ks] = *(const bh8*)(a.WswO + l * 16384 + ((nt * 4 + ks) * 64 + lane) * 8);
                    fx4 bb4 = *(const fx4*)&a.bo[l * 128 + n0];
#pragma unroll
                    for (int mt = 0; mt < 4; ++mt) {
                        fx4 acc = {0.f, 0.f, 0.f, 0.f};
#pragma unroll
                        for (int ks = 0; ks < 4; ++ks) acc = mfma16(wfr[ks], cfr[mt][ks], acc);
                        us4 rv = *(const us4*)&ACT[mt * 16 + ln][n0];
#pragma unroll
                        for (int r2 = 0; r2 < 4; ++r2)
                            Cv[i2][mt][r2] = acc[r2] + bb4[r2] + bu2f(rv[r2]);
                    }
                }
            }
            // LN1: partials (2 shuffles), ONE barrier, inline mean/inv
#pragma unroll
            for (int mt = 0; mt < 4; ++mt) {
                float s = 0.f, v = 0.f;
#pragma unroll
                for (int i2 = 0; i2 < 2; ++i2)
#pragma unroll
                    for (int r2 = 0; r2 < 4; ++r2) {
                        float aa = Cv[i2][mt][r2];
                        s += aa; v = fmaf(aa, aa, v);
                    }
                s += __shfl_xor(s, 16); v += __shfl_xor(v, 16);
                s += __shfl_xor(s, 32); v += __shfl_xor(v, 32);
                if (lane < 16) LNp2[mt * 16 + ln][w] = float2{s, v};
            }
            __syncthreads();
            {
                float mean4[4], inv4[4];
#pragma unroll
                for (int mt = 0; mt < 4; ++mt) {
                    int row = mt * 16 + ln;
                    float2 a0 = LNp2[row][0], a1 = LNp2[row][1];
                    float2 a2 = LNp2[row][2], a3 = LNp2[row][3];
                    float s = (a0.x + a1.x) + (a2.x + a3.x);
                    float v = (a0.y + a1.y) + (a2.y + a3.y);
                    float mean = s * (1.0f / 128.0f);
                    mean4[mt] = mean;
                    inv4[mt] = rsqrtf(v * (1.0f / 128.0f) - mean * mean + 1e-5f);
                }
#pragma unroll
                for (int i2 = 0; i2 < 2; ++i2) {
                    int n0 = (w * 2 + i2) * 16 + q * 4;
                    fx4 gg = *(const fx4*)&a.ln1g[l * 128 + n0];
                    fx4 be = *(const fx4*)&a.ln1b[l * 128 + n0];
#pragma unroll
                    for (int mt = 0; mt < 4; ++mt) {
                        us4 o;
#pragma unroll
                        for (int r2 = 0; r2 < 4; ++r2)
                            o[r2] = f2b((Cv[i2][mt][r2] - mean4[mt]) * inv4[mt] * gg[r2] + be[r2]);
                        *(us4*)&Kb[mt * 16 + ln][n0] = o;
                    }
                }
            }
            __syncthreads();

            // ================= FF (8 chunks of 128 hidden) ==================
            bh8 hfr[4][4];
#pragma unroll
            for (int mt = 0; mt < 4; ++mt)
#pragma unroll
                for (int ks = 0; ks < 4; ++ks)
                    hfr[mt][ks] = *(const bh8*)&Kb[mt * 16 + ln][ks * 32 + q * 8];
            fx4 f2a[2][4];
#pragma unroll
            for (int i2 = 0; i2 < 2; ++i2)
#pragma unroll
                for (int mt = 0; mt < 4; ++mt) f2a[i2][mt] = fx4{0.f, 0.f, 0.f, 0.f};
            for (int ch = 0; ch < 8; ++ch) {
                unsigned short (*dst)[STRD] = (ch & 1) ? Vb : Qb;
                bh8 w1fr[2][4];
#pragma unroll
                for (int i2 = 0; i2 < 2; ++i2) {
                    int ntg = ch * 8 + w * 2 + i2;
#pragma unroll
                    for (int ks = 0; ks < 4; ++ks)
                        w1fr[i2][ks] = *(const bh8*)(a.Wsw1 + l * 131072 + ((ntg * 4 + ks) * 64 + lane) * 8);
                }
#pragma unroll
                for (int mt = 0; mt < 4; ++mt) {
#pragma unroll
                    for (int i2 = 0; i2 < 2; ++i2) {
                        fx4 acc = {0.f, 0.f, 0.f, 0.f};
#pragma unroll
                        for (int ks = 0; ks < 4; ++ks) acc = mfma16(w1fr[i2][ks], hfr[mt][ks], acc);
                        int nl0 = (w * 2 + i2) * 16 + q * 4;
                        fx4 bb4 = *(const fx4*)&a.b1[l * HID_SZ + ch * 128 + nl0];
                        us4 o;
#pragma unroll
                        for (int r2 = 0; r2 < 4; ++r2) {
                            float vv = acc[r2] + bb4[r2];
                            o[r2] = f2b(vv > 0.f ? vv : 0.f);
                        }
                        *(us4*)&dst[mt * 16 + ln][nl0] = o;
                    }
                }
                __syncthreads();
                bh8 w2fr[2][4];
#pragma unroll
                for (int i2 = 0; i2 < 2; ++i2)
#pragma unroll
                    for (int ks = 0; ks < 4; ++ks)
                        w2fr[i2][ks] = *(const bh8*)(a.Wsw2 + l * 131072 +
                            (((w * 2 + i2) * 32 + ch * 4 + ks) * 64 + lane) * 8);
#pragma unroll
                for (int mt = 0; mt < 4; ++mt) {
                    bh8 ffr[4];
#pragma unroll
                    for (int ks = 0; ks < 4; ++ks)
                        ffr[ks] = *(const bh8*)&dst[mt * 16 + ln][ks * 32 + q * 8];
#pragma unroll
                    for (int i2 = 0; i2 < 2; ++i2)
#pragma unroll
                        for (int ks = 0; ks < 4; ++ks)
                            f2a[i2][mt] = mfma16(w2fr[i2][ks], ffr[ks], f2a[i2][mt]);
                }
                // no trailing barrier: ping-pong buffered
            }
            // epilogue: + b2 + H residual, LN2 -> ACT
            fx4 Cv2[2][4];
#pragma unroll
            for (int i2 = 0; i2 < 2; ++i2) {
                int n0 = (w * 2 + i2) * 16 + q * 4;
                fx4 bb4 = *(const fx4*)&a.b2p[l * 128 + n0];
#pragma unroll
                for (int mt = 0; mt < 4; ++mt) {
                    us4 rv = *(const us4*)&Kb[mt * 16 + ln][n0];
#pragma unroll
                    for (int r2 = 0; r2 < 4; ++r2)
                        Cv2[i2][mt][r2] = f2a[i2][mt][r2] + bb4[r2] + bu2f(rv[r2]);
                }
            }
#pragma unroll
            for (int mt = 0; mt < 4; ++mt) {
                float s = 0.f, v = 0.f;
#pragma unroll
                for (int i2 = 0; i2 < 2; ++i2)
#pragma unroll
                    for (int r2 = 0; r2 < 4; ++r2) {
                        float aa = Cv2[i2][mt][r2];
                        s += aa; v = fmaf(aa, aa, v);
                    }
                s += __shfl_xor(s, 16); v += __shfl_xor(v, 16);
                s += __shfl_xor(s, 32); v += __shfl_xor(v, 32);
                if (lane < 16) LNp2[mt * 16 + ln][w] = float2{s, v};
            }
            __syncthreads();
            {
                float mean4[4], inv4[4];
#pragma unroll
                for (int mt = 0; mt < 4; ++mt) {
                    int row = mt * 16 + ln;
                    float2 a0 = LNp2[row][0], a1 = LNp2[row][1];
                    float2 a2 = LNp2[row][2], a3 = LNp2[row][3];
                    float s = (a0.x + a1.x) + (a2.x + a3.x);
                    float v = (a0.y + a1.y) + (a2.y + a3.y);
                    float mean = s * (1.0f / 128.0f);
                    mean4[mt] = mean;
                    inv4[mt] = rsqrtf(v * (1.0f / 128.0f) - mean * mean + 1e-5f);
                }
#pragma unroll
                for (int i2 = 0; i2 < 2; ++i2) {
                    int n0 = (w * 2 + i2) * 16 + q * 4;
                    fx4 gg = *(const fx4*)&a.ln2g[l * 128 + n0];
                    fx4 be = *(const fx4*)&a.ln2b[l * 128 + n0];
#pragma unroll
                    for (int mt = 0; mt < 4; ++mt) {
                        us4 o;
#pragma unroll
                        for (int r2 = 0; r2 < 4; ++r2)
                            o[r2] = f2b((Cv2[i2][mt][r2] - mean4[mt]) * inv4[mt] * gg[r2] + be[r2]);
                        *(us4*)&ACT[mt * 16 + ln][n0] = o;
                    }
                }
            }
            __syncthreads();
        }

        // ============ head partial dot: wave w handles batch bbase + w =====
        {
            int bg = bbase + w;
            float part = 0.f;
            int srow = lane >> 2, c0 = (lane & 3) * 32;
#pragma unroll
            for (int i = 0; i < 4; ++i) {
                bh8 av = *(const bh8*)&ACT[w * 16 + srow][c0 + i * 8];
                int fl = srow * 128 + c0 + i * 8;
#pragma unroll
                for (int e = 0; e < 8; ++e)
                    part = fmaf(bu2f((unsigned short)av[e]), a.Wf[fl + e], part);
            }
            if (lane < GCN_SZ)
                part = fmaf(a.gcn[(size_t)bg * GCN_SZ + lane], a.Wf[2048 + lane], part);
#pragma unroll
            for (int off = 32; off; off >>= 1) part += __shfl_xor(part, off);
            if (lane == 0) a.acc1[bg] = part;
        }
        __syncthreads();   // ACT WAR vs next iteration's x+PE load
    }

    // ===================== P1b: BN-stats tiles =====================
    for (int st = blockIdx.x; st < SBLK; st += gridDim.x) {
        float* NUMs = (float*)ACT;            // [16][104]
        float* cred = (float*)Qb;             // [4][128]
        const int b0 = st * 16;
        const int j = t & 127, sg = t >> 7, s0 = sg * 8;

        for (int idx = t; idx < 16 * NUMF_SZ; idx += 256) {
            int r = idx / NUMF_SZ, f = idx - r * NUMF_SZ;
            NUMs[r * 104 + f] = a.num[(size_t)(b0 + r) * NUMF_SZ + f];
        }
        __syncthreads();

        float acc[8];
        float bnv = a.bnum[j];
#pragma unroll
        for (int r = 0; r < 8; ++r) acc[r] = bnv;
        for (int f = 0; f < NUMF_SZ; ++f) {
            float wv = a.Wn[f * 128 + j];
#pragma unroll
            for (int r = 0; r < 8; ++r) acc[r] = fmaf(NUMs[(s0 + r) * 104 + f], wv, acc[r]);
        }
        float lsum = 0.f, lsq = 0.f;
#pragma unroll
        for (int r = 0; r < 8; ++r) {
            lsum += acc[r];
            lsq = fmaf(acc[r], acc[r], lsq);
        }
        cred[sg * 128 + j] = lsum;
        cred[(2 + sg) * 128 + j] = lsq;
        __syncthreads();
        if (sg == 0) atomicAdd(&a.ssum[j], cred[j] + cred[128 + j]);
        else         atomicAdd(&a.ssq[j],  cred[256 + j] + cred[384 + j]);
        __syncthreads();
    }
    __threadfence();
    cg::this_grid().sync();

    // ====== P2: per-block BN-fold coefficients + final sigmoid rows ======
    {
        float* cS   = (float*)&Vb[0][0];      // 128 floats
        float* wv   = (float*)&Pb[0][0][0];   // 103 floats
        float* redw = (float*)&LNp2[0][0];    // 4 floats

        float C1p = 0.f;
        if (t < 128) {
            float sv = atomicAdd(&a.ssum[t], 0.f);   // device-coherent read
            float qv = atomicAdd(&a.ssq[t], 0.f);
            float mean = sv * (1.0f / (float)B_SZ);
            float var = qv * (1.0f / (float)B_SZ) - mean * mean;
            float inv = rsqrtf(var + 1e-5f);
            float wj = a.Wf[2088 + t];
            float gi = a.bng[t] * inv;
            float cj = gi * wj;
            cS[t] = cj;
            C1p = (a.bnb[t] - mean * gi) * wj + a.bnum[t] * cj;
        }
#pragma unroll
        for (int o = 32; o; o >>= 1) C1p += __shfl_xor(C1p, o);
        if (lane == 0) redw[w] = C1p;
        __syncthreads();
        const float C1 = redw[0] + redw[1] + redw[2] + redw[3] + a.bfin[0];
        if (t < NUMF_SZ) {
            float s2 = 0.f;
            for (int jj = 0; jj < 128; ++jj)
                s2 = fmaf(a.Wn[t * 128 + jj], cS[jj], s2);
            wv[t] = s2;
        }
        __syncthreads();

        for (int st = blockIdx.x; st < SBLK; st += gridDim.x) {
#pragma unroll
            for (int rr = 0; rr < 4; ++rr) {
                int b = st * 16 + w * 4 + rr;
                const float* nb = a.num + (size_t)b * NUMF_SZ;
                float part = nb[lane] * wv[lane];
                if (lane < NUMF_SZ - 64) part += nb[64 + lane] * wv[64 + lane];
#pragma unroll
                for (int o = 32; o; o >>= 1) part += __shfl_xor(part, o);
                if (lane == 0) {
                    float av = atomicAdd(&a.acc1[b], 0.f);   // coherent read
                    a.out[b] = 1.0f / (1.0f + __expf(-(av + part + C1)));
                }
            }
        }
    }
}

extern "C" void kernel_launch(void* const* d_in, const int* in_sizes, int n_in,
                              void* d_out, int out_size, void* d_ws, size_t ws_size,
                              hipStream_t stream)
{
    KArgs ka;
    ka.x    = (const float*)d_in[0];
    ka.gcn  = (const float*)d_in[1];
    ka.num  = (const float*)d_in[2];
    ka.Wq   = (const float*)d_in[3];
    ka.bq   = (const float*)d_in[4];
    ka.Wk   = (const float*)d_in[5];
    ka.bk   = (const float*)d_in[6];
    ka.Wv   = (const float*)d_in[7];
    ka.bv   = (const float*)d_in[8];
    ka.Wo   = (const float*)d_in[9];
    ka.bo   = (const float*)d_in[10];
    ka.ln1g = (const float*)d_in[11];
    ka.ln1b = (const float*)d_in[12];
    ka.W1   = (const float*)d_in[13];
    ka.b1   = (const float*)d_in[14];
    ka.W2   = (const float*)d_in[15];
    ka.b2p  = (const float*)d_in[16];
    ka.ln2g = (const float*)d_in[17];
    ka.ln2b = (const float*)d_in[18];
    ka.Wn   = (const float*)d_in[19];
    ka.bnum = (const float*)d_in[20];
    ka.bng  = (const float*)d_in[21];
    ka.bnb  = (const float*)d_in[22];
    ka.Wf   = (const float*)d_in[23];
    ka.bfin = (const float*)d_in[24];

    // ws: acc1 (8192 f32) | ssum(128) | ssq(128) | pad to 40960
    //     | swizzled bf16 weights | PE (8 KB)
    float* acc1 = (float*)d_ws;
    float* ssum = acc1 + B_SZ;
    float* ssq  = ssum + 128;
    unsigned short* wb = (unsigned short*)((char*)d_ws + 40960);
    ka.acc1 = acc1;
    ka.ssum = ssum;
    ka.ssq  = ssq;
    ka.WswQ = wb;
    ka.WswK = wb + 32768;
    ka.WswV = wb + 65536;
    ka.WswO = wb + 98304;
    ka.Wsw1 = wb + 131072;
    ka.Wsw2 = wb + 393216;
    ka.PEt  = (float*)((char*)d_ws + 40960 + 1310720);
    ka.out  = (float*)d_out;

    // Cooperative grid: min(512, capacity). 74KB LDS -> 2 blocks/CU -> 512
    // on a full 256-CU part; grid-stride loops keep any smaller grid correct.
    static int g_grid = 0;
    if (g_grid == 0) {
        int occ = 0;
        if (hipOccupancyMaxActiveBlocksPerMultiprocessor(&occ, mega_coop, 256, 0)
                != hipSuccess || occ < 1) occ = 2;
        int cus = 256;
        hipDeviceProp_t props;
        if (hipGetDeviceProperties(&props, 0) == hipSuccess && props.multiProcessorCount > 0)
            cus = props.multiProcessorCount;
        g_grid = occ * cus;
        if (g_grid > 512) g_grid = 512;
        if (g_grid < 1) g_grid = 256;
    }

    void* params[] = { (void*)&ka };
    hipLaunchCooperativeKernel(mega_coop, dim3(g_grid), dim3(256), params, 0u, stream);
}